// Round 5
// baseline (283.817 us; speedup 1.0000x reference)
//
#include <hip/hip_runtime.h>

// Conv2d 3x3 s1 p1 as implicit GEMM, bf16 MFMA, fp32 accumulate.
// N=32, Cin=128, H=W=56, Cout=256. M=100352, K=1152 (kh,kw outer / ci inner).
// R7: X bypasses LDS (A-frags are contiguous 16B in padded-NHWC xt -> direct
//     global->VGPR loads, L2-served). W via tiny double-buffered LDS (2x8KB).
//     Block 512m x 64co, 4 waves distinct-wm (no A dup). Software pipeline:
//     per kt: stage W(kt+1); load A(kt,kk1)->Q; MFMA kk0(P); load A(kt+1,kk0)->P;
//     MFMA kk1(Q); vmcnt(8); raw s_barrier (no vmcnt(0) drain).
//     Grid 784 = 196m x 4co, XCD swizzle keeps 4 co-blocks of an m-panel per XCD.

#define NB   32
#define CIN  128
#define HH   56
#define WWD  56
#define COUT 256
#define HWP  3136      // 56*56
#define KTOT 1152      // 9*128
#define HP   58        // padded spatial dim
#define XTN  (HP*HP*CIN)   // 430592 elems per image

typedef __bf16 bf16x8 __attribute__((ext_vector_type(8)));
typedef float  f32x4  __attribute__((ext_vector_type(4)));
typedef unsigned short u16;
typedef u16 u16x4 __attribute__((ext_vector_type(4)));
typedef u16 u16x8 __attribute__((ext_vector_type(8)));

__device__ __forceinline__ u16 f2b(float f) {
  unsigned u = __float_as_uint(f);
  u += 0x7fffu + ((u >> 16) & 1u);
  return (u16)(u >> 16);
}

__device__ __forceinline__ void load_lds16(const u16* g, u16* l) {
  __builtin_amdgcn_global_load_lds(
      (const __attribute__((address_space(1))) unsigned int*)g,
      (__attribute__((address_space(3))) unsigned int*)l, 16, 0, 0);
}

// x: [32][128][3136] f32 -> xt: [32][58][58][128] bf16 (NCHW -> padded NHWC + cvt)
// Interior only; border zeroed by k_transform_w.
__global__ __launch_bounds__(256) void k_transpose_x(const float* __restrict__ x,
                                                     u16* __restrict__ xt) {
  __shared__ u16 tile[64][68];   // row = c; 136B row stride
  const int n  = blockIdx.z;
  const int p0 = blockIdx.x * 64;
  const int c0 = blockIdx.y * 64;
  const int t  = threadIdx.x;

  const float* xp = x + (size_t)n * CIN * HWP + (size_t)c0 * HWP + p0;
  const int pl = (t & 15) * 4;   // pixel offset within tile
  const int cr = t >> 4;         // channel row 0..15 (+16j)
#pragma unroll
  for (int j = 0; j < 4; ++j) {
    int c = cr + j * 16;
    f32x4 v = *(const f32x4*)&xp[(size_t)c * HWP + pl];
    u16x4 h;
    h[0] = f2b(v[0]); h[1] = f2b(v[1]); h[2] = f2b(v[2]); h[3] = f2b(v[3]);
    *(u16x4*)&tile[c][pl] = h;
  }
  __syncthreads();
  u16* xb = xt + (size_t)n * XTN + c0;
  const int ch = (t & 7) * 8;    // channel chunk
  const int pr = t >> 3;         // pixel row 0..31 (+32j)
#pragma unroll
  for (int j = 0; j < 2; ++j) {
    int p  = pr + j * 32;
    int s  = p0 + p;
    int oh = s / WWD;
    int ow = s - oh * WWD;
    u16x8 o;
#pragma unroll
    for (int i = 0; i < 8; ++i) o[i] = tile[ch + i][p];
    *(u16x8*)&xb[((size_t)(oh + 1) * HP + (ow + 1)) * CIN + ch] = o;
  }
}

// w: [256][128][3][3] f32 -> Wt: [256][1152] bf16 with k = (kh*3+kw)*128 + ci
// Also zeroes the xt border (32 * 228 pixels * 128 ch = 933888 elems).
__global__ __launch_bounds__(256) void k_transform_w(const float* __restrict__ w,
                                                     u16* __restrict__ Wt,
                                                     u16* __restrict__ xt) {
  int o = blockIdx.x * 256 + threadIdx.x;
  if (o < COUT * KTOT) {
    int co  = o / KTOT;
    int rem = o - co * KTOT;
    int kk  = rem >> 7;      // (kh*3+kw)
    int ci  = rem & 127;
    int kh  = kk / 3;
    int kw  = kk - kh * 3;
    Wt[o] = f2b(w[(((size_t)co * CIN + ci) * 3 + kh) * 3 + kw]);
  }
#pragma unroll
  for (int j = 0; j < 4; ++j) {
    unsigned e = (unsigned)o + j * 294912u;
    if (e < 933888u) {
      unsigned n  = e / 29184u;         // 228*128
      unsigned rm = e - n * 29184u;
      unsigned bp = rm >> 7;            // border pixel 0..227
      unsigned ch = rm & 127u;
      unsigned ih, iw;
      if (bp < 58u)       { ih = 0;  iw = bp; }
      else if (bp < 116u) { ih = 57; iw = bp - 58u; }
      else { unsigned c2 = bp - 116u; ih = 1u + (c2 >> 1); iw = (c2 & 1u) ? 57u : 0u; }
      xt[(((size_t)n * HP + ih) * HP + iw) * CIN + ch] = (u16)0;
    }
  }
}

// ---- GEMM: grid 784 (196 m-tiles x 4 co-tiles), block 256 (4 waves).
// Block tile 512m x 64co; per-wave 128m x 64co (distinct wm -> A read once).
// A direct global->reg; W via 2x8KB LDS double buffer, XOR piece-swizzled.

__device__ __forceinline__ int uX_off(int kt) {
  int ksp = kt >> 1;
  int kh  = (ksp >= 6) ? 2 : ((ksp >= 3) ? 1 : 0);
  int kw  = ksp - kh * 3;
  return (kh * HP + kw) * CIN + ((kt & 1) << 6);
}

#define LD_A(SET_, uoff_) do { _Pragma("unroll") \
  for (int ti = 0; ti < 8; ++ti) \
    SET_[ti] = *(const bf16x8*)(xt + offA[ti] + (uoff_)); } while (0)

#define RD_W(buf_, kk_) do { _Pragma("unroll") \
  for (int tj = 0; tj < 4; ++tj) \
    bf[tj] = *(const bf16x8*)&lW[buf_][(tj * 16 + r) * 64 + (((kk_) * 4 + q) ^ r7) * 8]; } while (0)

#define MFMA_SET(SET_) do { _Pragma("unroll") \
  for (int ti = 0; ti < 8; ++ti) \
    { _Pragma("unroll") for (int tj = 0; tj < 4; ++tj) \
      acc[ti][tj] = __builtin_amdgcn_mfma_f32_16x16x32_bf16( \
          SET_[ti], bf[tj], acc[ti][tj], 0, 0, 0); } } while (0)

__global__ __launch_bounds__(256, 2) void k_conv_gemm(
    const u16* __restrict__ xt, const u16* __restrict__ Wt,
    const float* __restrict__ bias, float* __restrict__ out) {
  __shared__ u16 lW[2][4096];   // 2 bufs x 64 co-rows x 64 k (8 KB each)

  const int tid  = threadIdx.x;
  const int wave = tid >> 6;
  const int lane = tid & 63;

  // XCD chunk swizzle (784 = 8*98, bijective). 4 consecutive orig = same m-panel
  // (by=0..3) -> same XCD -> X panel served from that XCD's L2.
  const int bid  = blockIdx.x;
  const int orig = (bid & 7) * 98 + (bid >> 3);
  const int bx   = orig >> 2;
  const int by   = orig & 3;
  const int m0   = bx * 512;
  const int co0  = by * 64;

  const int r  = lane & 15;
  const int q  = lane >> 4;
  const int r7 = r & 7;

  float bias_r[4];
#pragma unroll
  for (int tj = 0; tj < 4; ++tj) bias_r[tj] = bias[co0 + tj * 16 + r];

  // A per-lane element offsets for ti=0..7 (this wave's 128 m-rows)
  int offA[8];
#pragma unroll
  for (int ti = 0; ti < 8; ++ti) {
    const int m  = m0 + wave * 128 + ti * 16 + r;
    const int n  = m / HWP;
    const int s  = m - n * HWP;
    const int oh = s / WWD;
    const int ow = s - oh * WWD;
    offA[ti] = ((n * HP + oh) * HP + ow) * CIN + q * 8;
  }

  // W staging: wave handles co-rows wave*16 .. wave*16+15 (2 loads of 8 rows)
  const int rsub = lane >> 3;
  const int pso  = ((lane & 7) ^ rsub) * 8;
  int pbW[2], ldoW[2];
#pragma unroll
  for (int c = 0; c < 2; ++c) {
    const int rowb = wave * 16 + c * 8;
    pbW[c]  = (co0 + rowb + rsub) * KTOT + pso;
    ldoW[c] = rowb * 64;
  }

  f32x4 acc[8][4];
#pragma unroll
  for (int i = 0; i < 8; ++i)
#pragma unroll
    for (int j = 0; j < 4; ++j) acc[i][j] = (f32x4){0.f, 0.f, 0.f, 0.f};

  bf16x8 P[8], Q[8], bf[4];

  // Prologue: stage W(0)->buf0 (2 loads), issue A(0,kk0)->P (8 loads).
  // vmcnt(8) drains bias+W2, leaves P8 in flight.
#pragma unroll
  for (int c = 0; c < 2; ++c) load_lds16(Wt + pbW[c], &lW[0][ldoW[c]]);
  LD_A(P, 0);
  asm volatile("s_waitcnt vmcnt(8)" ::: "memory");
  __builtin_amdgcn_s_barrier();

#pragma unroll 1
  for (int kt = 0; kt < 17; ++kt) {
    const int cur  = kt & 1;
    const int uxo  = uX_off(kt);
    const int uxoN = uX_off(kt + 1);
    // issue W-stage(kt+1) -> other buffer   [in flight: P8, W2]
#pragma unroll
    for (int c = 0; c < 2; ++c)
      load_lds16(Wt + pbW[c] + (kt + 1) * 64, &lW[cur ^ 1][ldoW[c]]);
    // issue A(kt, kk1) -> Q                 [P8, W2, Q8]
    LD_A(Q, uxo + 32);
    RD_W(cur, 0);
    MFMA_SET(P);            // compiler waits vmcnt(10) for P + lgkm for bf
    // issue A(kt+1, kk0) -> P               [W2, Q8, P8']
    LD_A(P, uxoN);
    RD_W(cur, 1);
    MFMA_SET(Q);            // compiler waits vmcnt(8): Q landed => W2 landed
    asm volatile("s_waitcnt vmcnt(8)" ::: "memory");   // W(kt+1) visible
    __builtin_amdgcn_s_barrier();                      // raw: no vmcnt(0) drain
  }
  // kt=17 peel: in flight [P8]; buffer (17&1)=1 holds W(17).
  {
    const int uxo = uX_off(17);
    LD_A(Q, uxo + 32);      // [P8, Q8]
    RD_W(1, 0);
    MFMA_SET(P);            // vmcnt(8) -> P landed
    RD_W(1, 1);
    MFMA_SET(Q);            // vmcnt(0)
  }

  // Epilogue: mfma(a=X, b=W) -> col(lane&15)=co, row(q*4+e)=m. f32x4 stores.
#pragma unroll
  for (int ti = 0; ti < 8; ++ti) {
    const int m4 = m0 + wave * 128 + ti * 16 + q * 4;
    const int n  = m4 / HWP;
    const int s  = m4 - n * HWP;
    float* op = out + (size_t)n * COUT * HWP + s;
#pragma unroll
    for (int tj = 0; tj < 4; ++tj) {
      const int co = co0 + tj * 16 + r;
      f32x4 v = acc[ti][tj];
      const float bv = bias_r[tj];
      v[0] += bv; v[1] += bv; v[2] += bv; v[3] += bv;
      *(f32x4*)(op + (size_t)co * HWP) = v;
    }
  }
}

extern "C" void kernel_launch(void* const* d_in, const int* in_sizes, int n_in,
                              void* d_out, int out_size, void* d_ws, size_t ws_size,
                              hipStream_t stream) {
  const float* x    = (const float*)d_in[0];
  const float* w    = (const float*)d_in[1];
  const float* bias = (const float*)d_in[2];
  float* out        = (float*)d_out;

  u16* xt = (u16*)d_ws;                       // 13,778,944 bf16 = 27.6 MB (padded NHWC)
  u16* Wt = xt + (size_t)NB * XTN;            // 294,912 bf16

  k_transform_w<<<dim3(1152), dim3(256), 0, stream>>>(w, Wt, xt);
  k_transpose_x<<<dim3(49, 2, 32), dim3(256), 0, stream>>>(x, xt);
  k_conv_gemm<<<dim3(784), dim3(256), 0, stream>>>(xt, Wt, bias, out);
}

// Round 6
// 223.079 us; speedup vs baseline: 1.2723x; 1.2723x over previous
//
#include <hip/hip_runtime.h>

// Conv2d 3x3 s1 p1 as implicit GEMM, bf16 MFMA, fp32 accumulate.
// N=32, Cin=128, H=W=56, Cout=256. M=100352, K=1152 (kh,kw outer / ci inner).
// R8: 8-phase-style counted-vmcnt schedule at tail-free geometry.
//     Block 256m x 128co, 8 waves (2M x 4N), wave tile 128x32, BK=64.
//     Triple-buffered A (3x32KB) + B (3x16KB) = 144 KB dynamic LDS.
//     Per K-tile: 2 phases {ds_read; stage 3 chunks; s_barrier; lgkmcnt(0);
//     setprio(1); 16 MFMA; setprio(0); s_barrier}; vmcnt(6) once per K-tile
//     (never 0 in main loop; stage-ahead = 2 K-tiles, provably race-free).
//     Grid 784 = 8*98 bijective XCD swizzle (98% fill), padded-NHWC xt.

#define NB   32
#define CIN  128
#define HH   56
#define WWD  56
#define COUT 256
#define HWP  3136      // 56*56
#define KTOT 1152      // 9*128
#define HP   58        // padded spatial dim
#define XTN  (HP*HP*CIN)   // 430592 elems per image

typedef __bf16 bf16x8 __attribute__((ext_vector_type(8)));
typedef float  f32x4  __attribute__((ext_vector_type(4)));
typedef unsigned short u16;
typedef u16 u16x4 __attribute__((ext_vector_type(4)));
typedef u16 u16x8 __attribute__((ext_vector_type(8)));

__device__ __forceinline__ u16 f2b(float f) {
  unsigned u = __float_as_uint(f);
  u += 0x7fffu + ((u >> 16) & 1u);
  return (u16)(u >> 16);
}

__device__ __forceinline__ void load_lds16(const u16* g, u16* l) {
  __builtin_amdgcn_global_load_lds(
      (const __attribute__((address_space(1))) unsigned int*)g,
      (__attribute__((address_space(3))) unsigned int*)l, 16, 0, 0);
}

// x: [32][128][3136] f32 -> xt: [32][58][58][128] bf16 (NCHW -> padded NHWC + cvt)
// Interior only; border zeroed by k_transform_w.
__global__ __launch_bounds__(256) void k_transpose_x(const float* __restrict__ x,
                                                     u16* __restrict__ xt) {
  __shared__ u16 tile[64][68];   // row = c; 136B row stride
  const int n  = blockIdx.z;
  const int p0 = blockIdx.x * 64;
  const int c0 = blockIdx.y * 64;
  const int t  = threadIdx.x;

  const float* xp = x + (size_t)n * CIN * HWP + (size_t)c0 * HWP + p0;
  const int pl = (t & 15) * 4;   // pixel offset within tile
  const int cr = t >> 4;         // channel row 0..15 (+16j)
#pragma unroll
  for (int j = 0; j < 4; ++j) {
    int c = cr + j * 16;
    f32x4 v = *(const f32x4*)&xp[(size_t)c * HWP + pl];
    u16x4 h;
    h[0] = f2b(v[0]); h[1] = f2b(v[1]); h[2] = f2b(v[2]); h[3] = f2b(v[3]);
    *(u16x4*)&tile[c][pl] = h;
  }
  __syncthreads();
  u16* xb = xt + (size_t)n * XTN + c0;
  const int ch = (t & 7) * 8;    // channel chunk
  const int pr = t >> 3;         // pixel row 0..31 (+32j)
#pragma unroll
  for (int j = 0; j < 2; ++j) {
    int p  = pr + j * 32;
    int s  = p0 + p;
    int oh = s / WWD;
    int ow = s - oh * WWD;
    u16x8 o;
#pragma unroll
    for (int i = 0; i < 8; ++i) o[i] = tile[ch + i][p];
    *(u16x8*)&xb[((size_t)(oh + 1) * HP + (ow + 1)) * CIN + ch] = o;
  }
}

// w: [256][128][3][3] f32 -> Wt: [256][1152] bf16 with k = (kh*3+kw)*128 + ci
// Also zeroes the xt border (32 * 228 pixels * 128 ch = 933888 elems).
__global__ __launch_bounds__(256) void k_transform_w(const float* __restrict__ w,
                                                     u16* __restrict__ Wt,
                                                     u16* __restrict__ xt) {
  int o = blockIdx.x * 256 + threadIdx.x;
  if (o < COUT * KTOT) {
    int co  = o / KTOT;
    int rem = o - co * KTOT;
    int kk  = rem >> 7;      // (kh*3+kw)
    int ci  = rem & 127;
    int kh  = kk / 3;
    int kw  = kk - kh * 3;
    Wt[o] = f2b(w[(((size_t)co * CIN + ci) * 3 + kh) * 3 + kw]);
  }
#pragma unroll
  for (int j = 0; j < 4; ++j) {
    unsigned e = (unsigned)o + j * 294912u;
    if (e < 933888u) {
      unsigned n  = e / 29184u;         // 228*128
      unsigned rm = e - n * 29184u;
      unsigned bp = rm >> 7;            // border pixel 0..227
      unsigned ch = rm & 127u;
      unsigned ih, iw;
      if (bp < 58u)       { ih = 0;  iw = bp; }
      else if (bp < 116u) { ih = 57; iw = bp - 58u; }
      else { unsigned c2 = bp - 116u; ih = 1u + (c2 >> 1); iw = (c2 & 1u) ? 57u : 0u; }
      xt[(((size_t)n * HP + ih) * HP + iw) * CIN + ch] = (u16)0;
    }
  }
}

// ---- GEMM helpers ----
__device__ __forceinline__ int uX_off(int kt) {
  int ksp = kt >> 1;
  int kh  = (ksp >= 6) ? 2 : ((ksp >= 3) ? 1 : 0);
  int kw  = ksp - kh * 3;
  return (kh * HP + kw) * CIN + ((kt & 1) << 6);
}

// LDS elem map: A bufs at {0,16384,32768} (256x64 each), B at 49152+{0,8192,16384}.
#define RD_B_PH() do { _Pragma("unroll") for (int kk = 0; kk < 2; ++kk) \
  { _Pragma("unroll") for (int tj = 0; tj < 2; ++tj) \
    b[kk][tj] = *(const bf16x8*)&lds[Boff + ((wn + tj * 16 + r) << 6) + (kk ? sw1 : sw0)]; } } while (0)

#define RD_A_PH(qm_) do { _Pragma("unroll") for (int kk = 0; kk < 2; ++kk) \
  { _Pragma("unroll") for (int ti = 0; ti < 4; ++ti) \
    a[kk][ti] = *(const bf16x8*)&lds[Aoff + ((wm + (qm_) * 64 + ti * 16 + r) << 6) + (kk ? sw1 : sw0)]; } } while (0)

#define MM_PH(qm_) do { _Pragma("unroll") for (int kk = 0; kk < 2; ++kk) \
  { _Pragma("unroll") for (int ti = 0; ti < 4; ++ti) \
    { _Pragma("unroll") for (int tj = 0; tj < 2; ++tj) \
      acc[(qm_) * 4 + ti][tj] = __builtin_amdgcn_mfma_f32_16x16x32_bf16( \
          a[kk][ti], b[kk][tj], acc[(qm_) * 4 + ti][tj], 0, 0, 0); } } } while (0)

#define STG_A(c_) load_lds16(xt + pbXc[c_] + ux2, &lds[sAoff + ((c_) << 12) + ldA])
#define STG_B(c_) load_lds16(Wt + pbWc[c_] + uw2, &lds[sBoff + ((c_) << 12) + ldA])

__global__ __launch_bounds__(512, 2) void k_conv_gemm(
    const u16* __restrict__ xt, const u16* __restrict__ Wt,
    const float* __restrict__ bias, float* __restrict__ out) {
  extern __shared__ u16 lds[];
  const int tid  = threadIdx.x;
  const int wave = tid >> 6;
  const int lane = tid & 63;

  // XCD chunk swizzle (784 = 8*98, bijective); co-pairs of one m-tile adjacent
  // -> same XCD -> shared X panel in that XCD's L2.
  const int bid  = blockIdx.x;
  const int orig = (bid & 7) * 98 + (bid >> 3);
  const int bx   = orig >> 1;
  const int by   = orig & 1;
  const int m0   = bx * 256;
  const int co0  = by * 128;

  const int r  = lane & 15;
  const int q  = lane >> 4;
  const int r7 = r & 7;
  const int wm = (wave >> 2) * 128;   // 0 or 128
  const int wn = (wave & 3) * 32;     // 0/32/64/96
  const int sw0 = (q ^ r7) * 8;
  const int sw1 = sw0 ^ 32;

  // staging lane map: 8 rows x 8 swizzled 16B pieces per instruction
  const int rsub = lane >> 3;
  const int pso  = ((lane & 7) ^ rsub) * 8;
  const int ldA  = wave << 9;         // wave's 1KB slice within a chunk

  int pbXc[4];
#pragma unroll
  for (int c = 0; c < 4; ++c) {
    const int rowb = c * 64 + wave * 8 + rsub;
    const int m  = m0 + rowb;
    const int n  = m / HWP;
    const int s  = m - n * HWP;
    const int oh = s / WWD;
    const int ow = s - oh * WWD;
    pbXc[c] = ((n * HP + oh) * HP + ow) * CIN + pso;
  }
  int pbWc[2];
#pragma unroll
  for (int c = 0; c < 2; ++c)
    pbWc[c] = (co0 + c * 64 + wave * 8 + rsub) * KTOT + pso;

  float bias_r[2];
#pragma unroll
  for (int tj = 0; tj < 2; ++tj) bias_r[tj] = bias[co0 + wn + tj * 16 + r];

  f32x4 acc[8][2];
#pragma unroll
  for (int i = 0; i < 8; ++i)
#pragma unroll
    for (int j = 0; j < 2; ++j) acc[i][j] = (f32x4){0.f, 0.f, 0.f, 0.f};

  // Prologue: stage kt0 -> bufs0, kt1 -> bufs1 (12 chunks, FIFO).
#pragma unroll
  for (int c = 0; c < 4; ++c) load_lds16(xt + pbXc[c], &lds[(c << 12) + ldA]);
#pragma unroll
  for (int c = 0; c < 2; ++c) load_lds16(Wt + pbWc[c], &lds[49152 + (c << 12) + ldA]);
#pragma unroll
  for (int c = 0; c < 4; ++c) load_lds16(xt + pbXc[c] + 64, &lds[16384 + (c << 12) + ldA]);
#pragma unroll
  for (int c = 0; c < 2; ++c) load_lds16(Wt + pbWc[c] + 64, &lds[57344 + (c << 12) + ldA]);
  asm volatile("s_waitcnt vmcnt(6)" ::: "memory");   // kt0 landed; kt1 in flight
  __builtin_amdgcn_s_barrier();

  bf16x8 a[2][4], b[2][2];
  int bA = 0, sA = 2;   // read buf kt%3; stage buf (kt+2)%3

#pragma unroll 1
  for (int kt = 0; kt < 16; ++kt) {
    const int Aoff  = bA << 14;
    const int Boff  = 49152 + (bA << 13);
    const int sAoff = sA << 14;
    const int sBoff = 49152 + (sA << 13);
    const int ux2   = uX_off(kt + 2);
    const int uw2   = (kt + 2) << 6;

    // ---- phase 0 (qm=0)
    RD_B_PH(); RD_A_PH(0);
    STG_A(0); STG_A(1); STG_A(2);
    __builtin_amdgcn_s_barrier();
    asm volatile("s_waitcnt lgkmcnt(0)" ::: "memory");
    __builtin_amdgcn_s_setprio(1);
    MM_PH(0);
    __builtin_amdgcn_s_setprio(0);
    __builtin_amdgcn_s_barrier();

    // ---- phase 1 (qm=1)
    RD_A_PH(1);
    STG_A(3); STG_B(0); STG_B(1);
    asm volatile("s_waitcnt vmcnt(6)" ::: "memory");  // kt+1 fully in LDS; kt+2 in flight
    __builtin_amdgcn_s_barrier();
    asm volatile("s_waitcnt lgkmcnt(0)" ::: "memory");
    __builtin_amdgcn_s_setprio(1);
    MM_PH(1);
    __builtin_amdgcn_s_setprio(0);
    __builtin_amdgcn_s_barrier();

    bA = (bA == 2) ? 0 : bA + 1;
    sA = (sA == 2) ? 0 : sA + 1;
  }

  // ---- kt=16 (bA=1): no staging; drain kt17's loads with vmcnt(0) at ph1.
  {
    const int Aoff = 1 << 14;
    const int Boff = 49152 + (1 << 13);
    RD_B_PH(); RD_A_PH(0);
    __builtin_amdgcn_s_barrier();
    asm volatile("s_waitcnt lgkmcnt(0)" ::: "memory");
    __builtin_amdgcn_s_setprio(1);
    MM_PH(0);
    __builtin_amdgcn_s_setprio(0);
    __builtin_amdgcn_s_barrier();
    RD_A_PH(1);
    asm volatile("s_waitcnt vmcnt(0)" ::: "memory");
    __builtin_amdgcn_s_barrier();
    asm volatile("s_waitcnt lgkmcnt(0)" ::: "memory");
    __builtin_amdgcn_s_setprio(1);
    MM_PH(1);
    __builtin_amdgcn_s_setprio(0);
    __builtin_amdgcn_s_barrier();
  }
  // ---- kt=17 (bA=2): data already guaranteed; no barriers needed.
  {
    const int Aoff = 2 << 14;
    const int Boff = 49152 + (2 << 13);
    RD_B_PH(); RD_A_PH(0);
    MM_PH(0);
    RD_A_PH(1);
    MM_PH(1);
  }

  // Epilogue: mfma(a=X, b=W) -> col(lane&15)=co, row(q*4+e)=m. f32x4 stores.
#pragma unroll
  for (int ti = 0; ti < 8; ++ti) {
    const int m4 = m0 + wm + ti * 16 + q * 4;
    const int n  = m4 / HWP;
    const int s  = m4 - n * HWP;
    float* op = out + (size_t)n * COUT * HWP + s;
#pragma unroll
    for (int tj = 0; tj < 2; ++tj) {
      const int co = co0 + wn + tj * 16 + r;
      f32x4 v = acc[ti][tj];
      const float bv = bias_r[tj];
      v[0] += bv; v[1] += bv; v[2] += bv; v[3] += bv;
      *(f32x4*)(op + (size_t)co * HWP) = v;
    }
  }
}

extern "C" void kernel_launch(void* const* d_in, const int* in_sizes, int n_in,
                              void* d_out, int out_size, void* d_ws, size_t ws_size,
                              hipStream_t stream) {
  const float* x    = (const float*)d_in[0];
  const float* w    = (const float*)d_in[1];
  const float* bias = (const float*)d_in[2];
  float* out        = (float*)d_out;

  u16* xt = (u16*)d_ws;                       // 13,778,944 bf16 = 27.6 MB (padded NHWC)
  u16* Wt = xt + (size_t)NB * XTN;            // 294,912 bf16

  static bool attr_done = false;
  if (!attr_done) {
    hipFuncSetAttribute(reinterpret_cast<const void*>(k_conv_gemm),
                        hipFuncAttributeMaxDynamicSharedMemorySize, 147456);
    attr_done = true;
  }

  k_transform_w<<<dim3(1152), dim3(256), 0, stream>>>(w, Wt, xt);
  k_transpose_x<<<dim3(49, 2, 32), dim3(256), 0, stream>>>(x, xt);
  k_conv_gemm<<<dim3(784), dim3(512), 147456, stream>>>(xt, Wt, bias, out);
}

// Round 7
// 216.717 us; speedup vs baseline: 1.3096x; 1.0294x over previous
//
#include <hip/hip_runtime.h>

// Conv2d 3x3 s1 p1 as implicit GEMM, bf16 MFMA, fp32 accumulate.
// N=32, Cin=128, H=W=56, Cout=256. M=100352, K=1152 (kh,kw outer / ci inner).
// R9: R5 skeleton (128x128 tile, 4 waves, single 32 KB LDS buffer, 2-sync/K-tile,
//     4 blocks/CU) with 32x32x16 MFMA (2495 vs 2075 TF ceiling, -17% matrix-pipe
//     time, half the MFMA instruction count; same LDS bytes, same 64-AGPR acc).
//     Padded-NHWC xt, f32x4 epilogue, pair-preserving XCD chunk swizzle.

#define NB   32
#define CIN  128
#define HH   56
#define WWD  56
#define COUT 256
#define HWP  3136      // 56*56
#define KTOT 1152      // 9*128
#define HP   58        // padded spatial dim
#define XTN  (HP*HP*CIN)   // 430592 elems per image

typedef __bf16 bf16x8 __attribute__((ext_vector_type(8)));
typedef float  f32x4  __attribute__((ext_vector_type(4)));
typedef float  f32x16 __attribute__((ext_vector_type(16)));
typedef unsigned short u16;
typedef u16 u16x4 __attribute__((ext_vector_type(4)));
typedef u16 u16x8 __attribute__((ext_vector_type(8)));

__device__ __forceinline__ u16 f2b(float f) {
  unsigned u = __float_as_uint(f);
  u += 0x7fffu + ((u >> 16) & 1u);
  return (u16)(u >> 16);
}

__device__ __forceinline__ void load_lds16(const u16* g, u16* l) {
  __builtin_amdgcn_global_load_lds(
      (const __attribute__((address_space(1))) unsigned int*)g,
      (__attribute__((address_space(3))) unsigned int*)l, 16, 0, 0);
}

// x: [32][128][3136] f32 -> xt: [32][58][58][128] bf16 (NCHW -> padded NHWC + cvt)
// Interior only; border zeroed by k_transform_w.
__global__ __launch_bounds__(256) void k_transpose_x(const float* __restrict__ x,
                                                     u16* __restrict__ xt) {
  __shared__ u16 tile[64][68];   // row = c; 136B row stride
  const int n  = blockIdx.z;
  const int p0 = blockIdx.x * 64;
  const int c0 = blockIdx.y * 64;
  const int t  = threadIdx.x;

  const float* xp = x + (size_t)n * CIN * HWP + (size_t)c0 * HWP + p0;
  const int pl = (t & 15) * 4;   // pixel offset within tile
  const int cr = t >> 4;         // channel row 0..15 (+16j)
#pragma unroll
  for (int j = 0; j < 4; ++j) {
    int c = cr + j * 16;
    f32x4 v = *(const f32x4*)&xp[(size_t)c * HWP + pl];
    u16x4 h;
    h[0] = f2b(v[0]); h[1] = f2b(v[1]); h[2] = f2b(v[2]); h[3] = f2b(v[3]);
    *(u16x4*)&tile[c][pl] = h;
  }
  __syncthreads();
  u16* xb = xt + (size_t)n * XTN + c0;
  const int ch = (t & 7) * 8;    // channel chunk
  const int pr = t >> 3;         // pixel row 0..31 (+32j)
#pragma unroll
  for (int j = 0; j < 2; ++j) {
    int p  = pr + j * 32;
    int s  = p0 + p;
    int oh = s / WWD;
    int ow = s - oh * WWD;
    u16x8 o;
#pragma unroll
    for (int i = 0; i < 8; ++i) o[i] = tile[ch + i][p];
    *(u16x8*)&xb[((size_t)(oh + 1) * HP + (ow + 1)) * CIN + ch] = o;
  }
}

// w: [256][128][3][3] f32 -> Wt: [256][1152] bf16 with k = (kh*3+kw)*128 + ci
// Also zeroes the xt border (32 * 228 pixels * 128 ch = 933888 elems).
__global__ __launch_bounds__(256) void k_transform_w(const float* __restrict__ w,
                                                     u16* __restrict__ Wt,
                                                     u16* __restrict__ xt) {
  int o = blockIdx.x * 256 + threadIdx.x;
  if (o < COUT * KTOT) {
    int co  = o / KTOT;
    int rem = o - co * KTOT;
    int kk  = rem >> 7;      // (kh*3+kw)
    int ci  = rem & 127;
    int kh  = kk / 3;
    int kw  = kk - kh * 3;
    Wt[o] = f2b(w[(((size_t)co * CIN + ci) * 3 + kh) * 3 + kw]);
  }
#pragma unroll
  for (int j = 0; j < 4; ++j) {
    unsigned e = (unsigned)o + j * 294912u;
    if (e < 933888u) {
      unsigned n  = e / 29184u;         // 228*128
      unsigned rm = e - n * 29184u;
      unsigned bp = rm >> 7;            // border pixel 0..227
      unsigned ch = rm & 127u;
      unsigned ih, iw;
      if (bp < 58u)       { ih = 0;  iw = bp; }
      else if (bp < 116u) { ih = 57; iw = bp - 58u; }
      else { unsigned c2 = bp - 116u; ih = 1u + (c2 >> 1); iw = (c2 & 1u) ? 57u : 0u; }
      xt[(((size_t)n * HP + ih) * HP + iw) * CIN + ch] = (u16)0;
    }
  }
}

// ---- GEMM: grid 1568 (784 m-tiles x 2 co-tiles), block 256 (4 waves).
// 128x128 tile, BK=64, 18 K-tiles. SINGLE 32 KB LDS buffer; per K-tile:
// sync (readers done) -> stage 32 KB via global_load_lds -> sync -> MFMA.
// 32x32x16 MFMA: per wave 2x2 frags, 4 k-steps of 16; 16 b128 reads + 16 MFMA.

__device__ __forceinline__ int uX_off(int kt) {
  int ksp = kt >> 1;
  int kh  = (ksp >= 6) ? 2 : ((ksp >= 3) ? 1 : 0);
  int kw  = ksp - kh * 3;
  return (kh * HP + kw) * CIN + ((kt & 1) << 6);
}

__global__ __launch_bounds__(256, 4) void k_conv_gemm(
    const u16* __restrict__ xt, const u16* __restrict__ Wt,
    const float* __restrict__ bias, float* __restrict__ out) {
  __shared__ u16 lW[8192];   // 128 rows x 64 k, 16B pieces XOR-swizzled
  __shared__ u16 lX[8192];

  const int tid  = threadIdx.x;
  const int wave = tid >> 6;
  const int lane = tid & 63;

  // XCD chunk swizzle (1568 = 8*196 exact, bijective). Decode keeps the two
  // co-tiles of one m-tile (by=0,1) adjacent -> same XCD -> shared X panel in L2.
  const int bid  = blockIdx.x;
  const int orig = (bid & 7) * 196 + (bid >> 3);
  const int bx   = orig >> 1;
  const int by   = orig & 1;
  const int m0   = bx * 128;
  const int co0  = by * 128;

  const int r31 = lane & 31;         // row within 32x32 frag
  const int q2  = lane >> 5;         // k-half selector
  const int r7b = lane & 7;          // XOR key (row & 7)
  const int wm = (wave & 1) * 64;    // m offset of this wave's 64x64
  const int wc = (wave >> 1) * 64;   // co offset

  // staging lane map: 8 rows x 8 swizzled 16B pieces per instruction
  const int rsub = lane >> 3;
  const int pso  = ((lane & 7) ^ rsub) * 8;

  int pbX[4], pbW[4], ldo[4];
#pragma unroll
  for (int c = 0; c < 4; ++c) {
    const int rowb = wave * 32 + c * 8;
    const int m  = m0 + rowb + rsub;
    const int n  = m / HWP;
    const int s  = m - n * HWP;
    const int oh = s / WWD;
    const int ow = s - oh * WWD;
    pbX[c] = ((n * HP + oh) * HP + ow) * CIN + pso;
    pbW[c] = (co0 + rowb + rsub) * KTOT + pso;
    ldo[c] = rowb * 64;
  }
  float bias_r[2];
#pragma unroll
  for (int fc = 0; fc < 2; ++fc) bias_r[fc] = bias[co0 + wc + fc * 32 + r31];

  // per-frag LDS base rows (elements)
  const int rbA0 = (wm + r31) * 64;
  const int rbB0 = (wc + r31) * 64;

  f32x16 acc[2][2];
#pragma unroll
  for (int i = 0; i < 2; ++i)
#pragma unroll
    for (int j = 0; j < 2; ++j)
#pragma unroll
      for (int e = 0; e < 16; ++e) acc[i][j][e] = 0.f;

#pragma unroll 1
  for (int kt = 0; kt < 18; ++kt) {
    const int uxo = uX_off(kt);
    const int uwo = kt * 64;
    __syncthreads();   // all waves done reading LDS from previous K-tile
#pragma unroll
    for (int c = 0; c < 4; ++c) {
      load_lds16(xt + pbX[c] + uxo, &lX[ldo[c]]);   // X first (higher latency)
      load_lds16(Wt + pbW[c] + uwo, &lW[ldo[c]]);
    }
    __syncthreads();   // drains vmcnt -> staged data visible

#pragma unroll
    for (int ks = 0; ks < 4; ++ks) {
      const int slot = ((ks * 2 + q2) ^ r7b) * 8;   // swizzled 16B piece offset
      bf16x8 a[2], b[2];
#pragma unroll
      for (int fm = 0; fm < 2; ++fm)
        a[fm] = *(const bf16x8*)&lX[rbA0 + fm * 2048 + slot];
#pragma unroll
      for (int fc = 0; fc < 2; ++fc)
        b[fc] = *(const bf16x8*)&lW[rbB0 + fc * 2048 + slot];
#pragma unroll
      for (int fm = 0; fm < 2; ++fm)
#pragma unroll
        for (int fc = 0; fc < 2; ++fc)
          acc[fm][fc] = __builtin_amdgcn_mfma_f32_32x32x16_bf16(
              a[fm], b[fc], acc[fm][fc], 0, 0, 0);
    }
  }

  // Epilogue: D col = lane&31 (co), row = (reg&3) + 8*(reg>>2) + 4*(lane>>5) (m).
  // Each reg-quad g -> 4 consecutive m at m = fm*32 + g*8 + q2*4. f32x4 stores.
#pragma unroll
  for (int fm = 0; fm < 2; ++fm) {
#pragma unroll
    for (int g = 0; g < 4; ++g) {
      const int m4 = m0 + wm + fm * 32 + g * 8 + q2 * 4;
      const int n  = m4 / HWP;
      const int s  = m4 - n * HWP;
      float* op = out + (size_t)n * COUT * HWP + s;
#pragma unroll
      for (int fc = 0; fc < 2; ++fc) {
        const int co = co0 + wc + fc * 32 + r31;
        const float bv = bias_r[fc];
        f32x4 v;
        v[0] = acc[fm][fc][g * 4 + 0] + bv;
        v[1] = acc[fm][fc][g * 4 + 1] + bv;
        v[2] = acc[fm][fc][g * 4 + 2] + bv;
        v[3] = acc[fm][fc][g * 4 + 3] + bv;
        *(f32x4*)(op + (size_t)co * HWP) = v;
      }
    }
  }
}

extern "C" void kernel_launch(void* const* d_in, const int* in_sizes, int n_in,
                              void* d_out, int out_size, void* d_ws, size_t ws_size,
                              hipStream_t stream) {
  const float* x    = (const float*)d_in[0];
  const float* w    = (const float*)d_in[1];
  const float* bias = (const float*)d_in[2];
  float* out        = (float*)d_out;

  u16* xt = (u16*)d_ws;                       // 13,778,944 bf16 = 27.6 MB (padded NHWC)
  u16* Wt = xt + (size_t)NB * XTN;            // 294,912 bf16

  k_transform_w<<<dim3(1152), dim3(256), 0, stream>>>(w, Wt, xt);
  k_transpose_x<<<dim3(49, 2, 32), dim3(256), 0, stream>>>(x, xt);
  k_conv_gemm<<<dim3(1568), dim3(256), 0, stream>>>(xt, Wt, bias, out);
}